// Round 1
// baseline (136.621 us; speedup 1.0000x reference)
//
#include <hip/hip_runtime.h>
#include <math.h>

#define HID 128
#define SPB 128   // samples per block
#define TPB 256   // threads per block (4 waves)
#define LDSTR 136 // padded LDS row stride (bf16 elems): 272B, 16B-aligned

typedef __bf16 bf16;
typedef bf16 bf16x8 __attribute__((ext_vector_type(8)));
typedef float floatx4 __attribute__((ext_vector_type(4)));

__device__ __forceinline__ float fast_tanh(float x) {
    // 1 - 2/(e^{2x}+1); stable at +/-inf, ~1e-6 rel error
    float e = __expf(2.0f * x);
    return 1.0f - 2.0f / (e + 1.0f);
}

__global__ __launch_bounds__(TPB, 1)
void lnn_kernel(const float* __restrict__ X,
                const float* __restrict__ W1,
                const float* __restrict__ b1,
                const float* __restrict__ W2,
                const float* __restrict__ b2,
                const float* __restrict__ W3,
                float* __restrict__ out,
                int B)
{
    // ~146 KB LDS total (gfx950: 160 KB/WG) -> 1 block/CU
    __shared__ __align__(16) bf16 sW2T[HID][LDSTR]; // [j][i] = W2[i][j]  (B-frags GEMM1)
    __shared__ __align__(16) bf16 sW2r[HID][LDSTR]; // [i][j] row-major   (B-frags GEMM2)
    __shared__ __align__(16) bf16 sH1 [SPB][LDSTR]; // tanh(feat@W1+b1)
    __shared__ __align__(16) bf16 sG2 [SPB][LDSTR]; // (1-h2^2)*W3
    __shared__ __align__(16) float sW1T[HID][4];    // [i][k] = W1[k][i]
    __shared__ float sB1[HID];
    __shared__ float sB2[HID];
    __shared__ float sW3[HID];
    __shared__ __align__(16) float sFeat[SPB][4];   // s1,c1,s2,c2
    __shared__ float sQd[SPB][2];                   // w1,w2

    const int tid = threadIdx.x;
    const int s0  = blockIdx.x * SPB;

    // ---- Phase 0: stage weights ----
    for (int e = tid; e < HID * 4; e += TPB) {
        int i = e >> 2, k = e & 3;
        sW1T[i][k] = W1[k * HID + i];
    }
    if (tid < HID) {
        sB1[tid] = b1[tid];
        sB2[tid] = b2[tid];
        sW3[tid] = W3[tid];
    }
    for (int e = tid; e < HID * HID; e += TPB) {
        int i = e >> 7, j = e & 127;
        bf16 v = (bf16)W2[e];
        sW2r[i][j] = v;
        sW2T[j][i] = v;
    }
    // ---- per-sample trig/state ----
    if (tid < SPB) {
        int g = s0 + tid;
        int gc = g < B ? g : (B - 1);
        float4 x = reinterpret_cast<const float4*>(X)[gc];
        float s1, c1, s2, c2;
        __sincosf(x.x, &s1, &c1);
        __sincosf(x.y, &s2, &c2);
        sFeat[tid][0] = s1; sFeat[tid][1] = c1;
        sFeat[tid][2] = s2; sFeat[tid][3] = c2;
        sQd[tid][0] = x.z;  sQd[tid][1] = x.w;
    }
    __syncthreads();

    // ---- Phase 1: H1 = tanh(feat @ W1 + b1) ----
    for (int e = tid; e < SPB * HID; e += TPB) {
        int s = e >> 7, j = e & 127;
        float4 w = *reinterpret_cast<const float4*>(&sW1T[j][0]);
        float z = sB1[j] + sFeat[s][0] * w.x + sFeat[s][1] * w.y
                         + sFeat[s][2] * w.z + sFeat[s][3] * w.w;
        sH1[s][j] = (bf16)fast_tanh(z);
    }
    __syncthreads();

    const int wv    = tid >> 6;
    const int lane  = tid & 63;
    const int lrow  = lane & 15;
    const int lquad = lane >> 4;
    const int m0    = wv * 32; // wave's 32-sample stripe

    floatx4 acc[2][8];
    #pragma unroll
    for (int mt = 0; mt < 2; ++mt)
        #pragma unroll
        for (int nt = 0; nt < 8; ++nt)
            acc[mt][nt] = floatx4{0.f, 0.f, 0.f, 0.f};

    // ---- Phase 2: GEMM1  Z2 = H1 @ W2 ----
    #pragma unroll
    for (int kt = 0; kt < 4; ++kt) {
        int kb = kt * 32 + lquad * 8;
        bf16x8 a0 = *reinterpret_cast<const bf16x8*>(&sH1[m0 + lrow][kb]);
        bf16x8 a1 = *reinterpret_cast<const bf16x8*>(&sH1[m0 + 16 + lrow][kb]);
        #pragma unroll
        for (int nt = 0; nt < 8; ++nt) {
            bf16x8 bf = *reinterpret_cast<const bf16x8*>(&sW2T[nt * 16 + lrow][kb]);
            acc[0][nt] = __builtin_amdgcn_mfma_f32_16x16x32_bf16(a0, bf, acc[0][nt], 0, 0, 0);
            acc[1][nt] = __builtin_amdgcn_mfma_f32_16x16x32_bf16(a1, bf, acc[1][nt], 0, 0, 0);
        }
    }

    // ---- Phase 3: G2 = (1 - tanh^2(Z2+b2)) * W3 ----
    #pragma unroll
    for (int mt = 0; mt < 2; ++mt)
        #pragma unroll
        for (int nt = 0; nt < 8; ++nt)
            #pragma unroll
            for (int r = 0; r < 4; ++r) {
                int srow = m0 + mt * 16 + lquad * 4 + r;
                int j = nt * 16 + lrow;
                float z = acc[mt][nt][r] + sB2[j];
                float h = fast_tanh(z);
                sG2[srow][j] = (bf16)((1.0f - h * h) * sW3[j]);
            }
    __syncthreads();

    // ---- Phase 4: GEMM2  S = G2 @ W2^T ----
    #pragma unroll
    for (int mt = 0; mt < 2; ++mt)
        #pragma unroll
        for (int nt = 0; nt < 8; ++nt)
            acc[mt][nt] = floatx4{0.f, 0.f, 0.f, 0.f};

    #pragma unroll
    for (int kt = 0; kt < 4; ++kt) {
        int kb = kt * 32 + lquad * 8;
        bf16x8 a0 = *reinterpret_cast<const bf16x8*>(&sG2[m0 + lrow][kb]);
        bf16x8 a1 = *reinterpret_cast<const bf16x8*>(&sG2[m0 + 16 + lrow][kb]);
        #pragma unroll
        for (int nt = 0; nt < 8; ++nt) {
            bf16x8 bf = *reinterpret_cast<const bf16x8*>(&sW2r[nt * 16 + lrow][kb]);
            acc[0][nt] = __builtin_amdgcn_mfma_f32_16x16x32_bf16(a0, bf, acc[0][nt], 0, 0, 0);
            acc[1][nt] = __builtin_amdgcn_mfma_f32_16x16x32_bf16(a1, bf, acc[1][nt], 0, 0, 0);
        }
    }

    // ---- Phase 5: dV/dfeat partials: g1 = (1-h1^2)*S ; dV_k = sum_i W1[k][i] g1_i ----
    float p[2][4][4] = {};
    #pragma unroll
    for (int mt = 0; mt < 2; ++mt)
        #pragma unroll
        for (int nt = 0; nt < 8; ++nt)
            #pragma unroll
            for (int r = 0; r < 4; ++r) {
                int srow = m0 + mt * 16 + lquad * 4 + r;
                int i = nt * 16 + lrow;
                float h1 = (float)sH1[srow][i];
                float g1 = (1.0f - h1 * h1) * acc[mt][nt][r];
                float4 w = *reinterpret_cast<const float4*>(&sW1T[i][0]);
                p[mt][r][0] += g1 * w.x;
                p[mt][r][1] += g1 * w.y;
                p[mt][r][2] += g1 * w.z;
                p[mt][r][3] += g1 * w.w;
            }

    // butterfly-reduce over the 16 lanes of each quad-group (covers all 128 i)
    #pragma unroll
    for (int mt = 0; mt < 2; ++mt)
        #pragma unroll
        for (int r = 0; r < 4; ++r)
            #pragma unroll
            for (int k = 0; k < 4; ++k) {
                float v = p[mt][r][k];
                v += __shfl_xor(v, 1);
                v += __shfl_xor(v, 2);
                v += __shfl_xor(v, 4);
                v += __shfl_xor(v, 8);
                p[mt][r][k] = v;
            }

    // ---- Phase 6: analytic dynamics + solve; 8 writer lanes per 16-lane group ----
    int idx = lane & 15;
    if (idx < 8) {
        int mt = idx >> 2, r = idx & 3;
        int srow = m0 + mt * 16 + lquad * 4 + r;
        int g = s0 + srow;
        if (g < B) {
            float s1 = sFeat[srow][0], c1 = sFeat[srow][1];
            float s2 = sFeat[srow][2], c2 = sFeat[srow][3];
            float w1 = sQd[srow][0],  w2 = sQd[srow][1];
            float cosD = c1 * c2 + s1 * s2;
            float sinD = s1 * c2 - c1 * s2;
            float dV0 = p[mt][r][0], dV1 = p[mt][r][1];
            float dV2 = p[mt][r][2], dV3 = p[mt][r][3];
            float dVt1 = dV0 * c1 - dV1 * s1;           // dV/dt1
            float dVt2 = dV2 * c2 - dV3 * s2;           // dV/dt2
            float sT = w1 * w2 * sinD;                  // dT/dt1 = -sT, dT/dt2 = +sT
            float cw = sinD * (w2 - w1);
            float rhs1 = (-sT - dVt1) - w2 * cw;        // dL/dq - C
            float rhs2 = ( sT - dVt2) - w1 * cw;
            float det = 2.0f - cosD * cosD;             // det(M), in [1,2]
            float inv = 1.0f / det;
            float qdd1 = (rhs1 - cosD * rhs2) * inv;
            float qdd2 = (2.0f * rhs2 - cosD * rhs1) * inv;
            float4 o = make_float4(w1, w2, qdd1, qdd2);
            *reinterpret_cast<float4*>(&out[4 * g]) = o;
        }
    }
}

extern "C" void kernel_launch(void* const* d_in, const int* in_sizes, int n_in,
                              void* d_out, int out_size, void* d_ws, size_t ws_size,
                              hipStream_t stream) {
    const float* X  = (const float*)d_in[0];
    const float* W1 = (const float*)d_in[1];
    const float* b1 = (const float*)d_in[2];
    const float* W2 = (const float*)d_in[3];
    const float* b2 = (const float*)d_in[4];
    const float* W3 = (const float*)d_in[5];
    // d_in[6] = b3: constant offset on V, vanishes in all gradients
    float* out = (float*)d_out;
    int B = in_sizes[0] / 4;
    int grid = (B + SPB - 1) / SPB;
    lnn_kernel<<<grid, TPB, 0, stream>>>(X, W1, b1, W2, b2, W3, out, B);
}

// Round 2
// 119.494 us; speedup vs baseline: 1.1433x; 1.1433x over previous
//
#include <hip/hip_runtime.h>
#include <math.h>

#define HID 128
#define SPB 128   // samples per block
#define TPB 1024  // 16 waves -> 4 waves/SIMD at 1 block/CU

typedef __bf16 bf16;
typedef bf16 bf16x8 __attribute__((ext_vector_type(8)));
typedef float floatx4 __attribute__((ext_vector_type(4)));

__device__ __forceinline__ float fast_tanh(float x) {
    // 1 - 2/(e^{2x}+1); stable at +/-inf
    float e = __expf(2.0f * x);
    return 1.0f - 2.0f / (e + 1.0f);
}

// Fragment-ordered LDS layouts (everything is [tile][lane] of bf16x8 => all
// MFMA-side LDS traffic is contiguous ds_read_b128 / ds_write_b128):
//   B-frag tile (kt,nt), lane l holds B[k=kt*32+(l>>4)*8+idx][n=nt*16+(l&15)]
//   A-frag tile (mtile,kt), lane l holds A[m=mtile*16+(l&15)][k=kt*32+(l>>4)*8+idx]
//   C layout: col = lane&15, row = (lane>>4)*4 + reg

__global__ __launch_bounds__(TPB, 4)
void lnn_kernel(const float* __restrict__ X,
                const float* __restrict__ W1,
                const float* __restrict__ b1,
                const float* __restrict__ W2,
                const float* __restrict__ b2,
                const float* __restrict__ W3,
                float* __restrict__ out,
                int B)
{
    __shared__ __align__(16) bf16 sW2B1[4*8*64*8]; // GEMM1 B frags (W2 col-segments) 32KB
    __shared__ __align__(16) bf16 sW2B2[4*8*64*8]; // GEMM2 B frags (W2 row-segments) 32KB
    __shared__ __align__(16) bf16 sH1 [8*4*64*8];  // H1 A-frags [mtile][kt][lane][idx] 32KB
    __shared__ __align__(16) bf16 sG2 [8*4*64*8];  // G2 A-frags 32KB
    __shared__ float sW1s[4][HID];                 // SoA: sW1s[k][i] = W1[k*128+i]
    __shared__ float sB1[HID];
    __shared__ float sB2[HID];
    __shared__ float sW3[HID];
    __shared__ __align__(16) float sFeat[SPB][4];  // s1,c1,s2,c2
    __shared__ __align__(16) float sDV[2][SPB][4]; // dV/dfeat halves (nth 0/1)

    const int tid   = threadIdx.x;
    const int w     = tid >> 6;
    const int lane  = tid & 63;
    const int lrow  = lane & 15;
    const int lquad = lane >> 4;
    const int mtile = w >> 1;       // 0..7 (16-sample stripe)
    const int nth   = w & 1;        // n-half: nt in [nth*4, nth*4+4)
    const int m0    = mtile * 16;
    const int s0    = blockIdx.x * SPB;

    // ---- Phase 0: stage weights + per-sample trig ----
    if (tid < 512)      ((float*)sW1s)[tid] = W1[tid];      // W1 already [4][128] SoA
    else if (tid < 640) sB1[tid - 512] = b1[tid - 512];
    else if (tid < 768) sB2[tid - 640] = b2[tid - 640];
    else if (tid < 896) sW3[tid - 768] = W3[tid - 768];

    float xz = 0.f, xw = 0.f; // kept in regs for phase 6 (tid<128 threads)
    if (tid < SPB) {
        int g  = s0 + tid;
        int gc = g < B ? g : (B - 1);
        float4 x = reinterpret_cast<const float4*>(X)[gc];
        float s1, c1, s2, c2;
        __sincosf(x.x, &s1, &c1);
        __sincosf(x.y, &s2, &c2);
        sFeat[tid][0] = s1; sFeat[tid][1] = c1;
        sFeat[tid][2] = s2; sFeat[tid][3] = c2;
        xz = x.z; xw = x.w;
    }

    // W2 frags: wave w stages tiles {2w, 2w+1} in both orientations
    #pragma unroll
    for (int tt = 0; tt < 2; ++tt) {
        int t  = 2 * w + tt;
        int kt = t >> 3, nt = t & 7;
        // GEMM1 B-frag: column segment W2[k][n], k varies (stride-512B loads;
        // per idx a wave touches 4 rows x 64B contiguous -> coalesces to 4 lines)
        bf16x8 f;
        #pragma unroll
        for (int idx = 0; idx < 8; ++idx)
            f[idx] = (bf16)W2[(kt * 32 + lquad * 8 + idx) * HID + nt * 16 + lrow];
        *reinterpret_cast<bf16x8*>(&sW2B1[(t * 64 + lane) * 8]) = f;
        // GEMM2 B-frag: row segment W2[n][k] -> two float4 loads (fully coalesced)
        const float4* rp = reinterpret_cast<const float4*>(
            &W2[(nt * 16 + lrow) * HID + kt * 32 + lquad * 8]);
        float4 r0 = rp[0], r1 = rp[1];
        bf16x8 g;
        g[0] = (bf16)r0.x; g[1] = (bf16)r0.y; g[2] = (bf16)r0.z; g[3] = (bf16)r0.w;
        g[4] = (bf16)r1.x; g[5] = (bf16)r1.y; g[6] = (bf16)r1.z; g[7] = (bf16)r1.w;
        *reinterpret_cast<bf16x8*>(&sW2B2[(t * 64 + lane) * 8]) = g;
    }
    __syncthreads();

    // ---- Phase 1: H1 = tanh(feat @ W1 + b1), written directly as A-frags ----
    {
        int srow = m0 + lrow;
        float f0 = sFeat[srow][0], f1 = sFeat[srow][1];
        float f2 = sFeat[srow][2], f3 = sFeat[srow][3];
        #pragma unroll
        for (int c = 0; c < 2; ++c) {
            int kt = nth * 2 + c;
            bf16x8 hf;
            #pragma unroll
            for (int idx = 0; idx < 8; ++idx) {
                int j = kt * 32 + lquad * 8 + idx;
                float z = sB1[j] + f0 * sW1s[0][j] + f1 * sW1s[1][j]
                                 + f2 * sW1s[2][j] + f3 * sW1s[3][j];
                hf[idx] = (bf16)fast_tanh(z);
            }
            *reinterpret_cast<bf16x8*>(&sH1[((mtile * 4 + kt) * 64 + lane) * 8]) = hf;
        }
    }
    __syncthreads();

    // ---- Phase 2: GEMM1  Z2 = H1 @ W2  (wave: 1 m-tile x 4 n-tiles) ----
    floatx4 acc[4];
    #pragma unroll
    for (int n = 0; n < 4; ++n) acc[n] = floatx4{0.f, 0.f, 0.f, 0.f};
    #pragma unroll
    for (int kt = 0; kt < 4; ++kt) {
        bf16x8 a = *reinterpret_cast<const bf16x8*>(&sH1[((mtile * 4 + kt) * 64 + lane) * 8]);
        #pragma unroll
        for (int n = 0; n < 4; ++n) {
            int nt = nth * 4 + n;
            bf16x8 bfr = *reinterpret_cast<const bf16x8*>(&sW2B1[((kt * 8 + nt) * 64 + lane) * 8]);
            acc[n] = __builtin_amdgcn_mfma_f32_16x16x32_bf16(a, bfr, acc[n], 0, 0, 0);
        }
    }

    // ---- Phase 3: G2 = (1 - tanh^2(Z2+b2)) * W3, written as A-frags ----
    #pragma unroll
    for (int n = 0; n < 4; ++n) {
        int nt = nth * 4 + n;
        int j  = nt * 16 + lrow;
        float bb = sB2[j], w3 = sW3[j];
        int kt2   = j >> 5;
        int lhi   = ((j >> 3) & 3) << 4;
        int idx2  = j & 7;
        #pragma unroll
        for (int r = 0; r < 4; ++r) {
            int srow15 = lquad * 4 + r;
            float h  = fast_tanh(acc[n][r] + bb);
            float g2 = (1.0f - h * h) * w3;
            sG2[((mtile * 4 + kt2) * 64 + (srow15 | lhi)) * 8 + idx2] = (bf16)g2;
        }
    }
    __syncthreads();

    // ---- Phase 4: GEMM2  S = G2 @ W2^T ----
    #pragma unroll
    for (int n = 0; n < 4; ++n) acc[n] = floatx4{0.f, 0.f, 0.f, 0.f};
    #pragma unroll
    for (int kt = 0; kt < 4; ++kt) {
        bf16x8 a = *reinterpret_cast<const bf16x8*>(&sG2[((mtile * 4 + kt) * 64 + lane) * 8]);
        #pragma unroll
        for (int n = 0; n < 4; ++n) {
            int nt = nth * 4 + n;
            bf16x8 bfr = *reinterpret_cast<const bf16x8*>(&sW2B2[((kt * 8 + nt) * 64 + lane) * 8]);
            acc[n] = __builtin_amdgcn_mfma_f32_16x16x32_bf16(a, bfr, acc[n], 0, 0, 0);
        }
    }

    // ---- Phase 5: g1 = (1-h1^2)*S ; dV_k partials + 16-lane butterfly ----
    float p[4][4] = {}; // [r][k]
    #pragma unroll
    for (int n = 0; n < 4; ++n) {
        int nt = nth * 4 + n;
        int i  = nt * 16 + lrow;
        float w10 = sW1s[0][i], w11 = sW1s[1][i], w12 = sW1s[2][i], w13 = sW1s[3][i];
        int kt2  = i >> 5;
        int lhi  = ((i >> 3) & 3) << 4;
        int idx2 = i & 7;
        #pragma unroll
        for (int r = 0; r < 4; ++r) {
            int srow15 = lquad * 4 + r;
            float h1 = (float)sH1[((mtile * 4 + kt2) * 64 + (srow15 | lhi)) * 8 + idx2];
            float g1 = (1.0f - h1 * h1) * acc[n][r];
            p[r][0] += g1 * w10; p[r][1] += g1 * w11;
            p[r][2] += g1 * w12; p[r][3] += g1 * w13;
        }
    }
    #pragma unroll
    for (int r = 0; r < 4; ++r)
        #pragma unroll
        for (int k = 0; k < 4; ++k) {
            float v = p[r][k];
            v += __shfl_xor(v, 1);
            v += __shfl_xor(v, 2);
            v += __shfl_xor(v, 4);
            v += __shfl_xor(v, 8);
            p[r][k] = v;
        }
    if (lrow == 0) {
        #pragma unroll
        for (int r = 0; r < 4; ++r) {
            int srow = m0 + lquad * 4 + r;
            *reinterpret_cast<float4*>(&sDV[nth][srow][0]) =
                make_float4(p[r][0], p[r][1], p[r][2], p[r][3]);
        }
    }
    __syncthreads();

    // ---- Phase 6: analytic dynamics + 2x2 solve (tid<128, same threads as X load) ----
    if (tid < SPB) {
        int g = s0 + tid;
        if (g < B) {
            float s1 = sFeat[tid][0], c1 = sFeat[tid][1];
            float s2 = sFeat[tid][2], c2 = sFeat[tid][3];
            float w1 = xz, w2 = xw;
            float dV0 = sDV[0][tid][0] + sDV[1][tid][0];
            float dV1 = sDV[0][tid][1] + sDV[1][tid][1];
            float dV2 = sDV[0][tid][2] + sDV[1][tid][2];
            float dV3 = sDV[0][tid][3] + sDV[1][tid][3];
            float cosD = c1 * c2 + s1 * s2;
            float sinD = s1 * c2 - c1 * s2;
            float dVt1 = dV0 * c1 - dV1 * s1;   // dV/dt1
            float dVt2 = dV2 * c2 - dV3 * s2;   // dV/dt2
            float sT = w1 * w2 * sinD;          // dT/dt1 = -sT, dT/dt2 = +sT
            float cw = sinD * (w2 - w1);
            float rhs1 = (-sT - dVt1) - w2 * cw;
            float rhs2 = ( sT - dVt2) - w1 * cw;
            float det = 2.0f - cosD * cosD;     // det(M) in [1,2]
            float inv = 1.0f / det;
            float qdd1 = (rhs1 - cosD * rhs2) * inv;
            float qdd2 = (2.0f * rhs2 - cosD * rhs1) * inv;
            *reinterpret_cast<float4*>(&out[4 * g]) = make_float4(w1, w2, qdd1, qdd2);
        }
    }
}

extern "C" void kernel_launch(void* const* d_in, const int* in_sizes, int n_in,
                              void* d_out, int out_size, void* d_ws, size_t ws_size,
                              hipStream_t stream) {
    const float* X  = (const float*)d_in[0];
    const float* W1 = (const float*)d_in[1];
    const float* b1 = (const float*)d_in[2];
    const float* W2 = (const float*)d_in[3];
    const float* b2 = (const float*)d_in[4];
    const float* W3 = (const float*)d_in[5];
    // d_in[6] = b3: constant offset on V, vanishes in all gradients
    float* out = (float*)d_out;
    int B = in_sizes[0] / 4;
    int grid = (B + SPB - 1) / SPB;
    lnn_kernel<<<grid, TPB, 0, stream>>>(X, W1, b1, W2, b2, W3, out, B);
}

// Round 3
// 109.031 us; speedup vs baseline: 1.2530x; 1.0960x over previous
//
#include <hip/hip_runtime.h>
#include <math.h>

#define HID 128
#define SPB 64    // samples per block
#define TPB 1024  // 16 waves; 2 blocks/CU -> 8 waves/SIMD (100% occupancy)

typedef __bf16 bf16;
typedef bf16 bf16x8 __attribute__((ext_vector_type(8)));
typedef float floatx4 __attribute__((ext_vector_type(4)));

__device__ __forceinline__ float fast_tanh(float x) {
    float e = __expf(2.0f * x);
    return 1.0f - 2.0f / (e + 1.0f);
}

// Fragment-ordered LDS layouts ([tile][lane] of bf16x8 => contiguous b128):
//   B-frag tile (kt,nt): lane l holds B[k=kt*32+(l>>4)*8+idx][n=nt*16+(l&15)]
//   A-frag tile (mt,kt):  lane l holds A[m=mt*16+(l&15)][k=kt*32+(l>>4)*8+idx]
//   C layout: col = lane&15, row = (lane>>4)*4 + reg
// Wave w: mtile = w>>2 (16-sample stripe), nq = w&3 (two n-tiles / one K-quarter)

__global__ __launch_bounds__(TPB, 8)
void lnn_kernel(const float* __restrict__ X,
                const float* __restrict__ W1,
                const float* __restrict__ b1,
                const float* __restrict__ W2,
                const float* __restrict__ b2,
                const float* __restrict__ W3,
                float* __restrict__ out,
                int B)
{
    __shared__ __align__(16) bf16 sW2F[4*8*64*8]; // 32KB: W2 frags, restaged between GEMMs
    __shared__ __align__(16) bf16 sH1 [4*4*64*8]; // 16KB: H1 A-frags
    __shared__ __align__(16) bf16 sG2 [4*4*64*8]; // 16KB: G2 A-frags, reused for G1
    __shared__ float sW1s[4][HID];                // 2KB, SoA
    __shared__ float sB1[HID];
    __shared__ float sB2[HID];
    __shared__ float sW3[HID];
    __shared__ __align__(16) float sFeat[SPB][4]; // s1,c1,s2,c2
    __shared__ __align__(16) float sDV[4][SPB][4];// dV/dfeat partials per K-quarter

    const int tid   = threadIdx.x;
    const int w     = tid >> 6;
    const int lane  = tid & 63;
    const int lrow  = lane & 15;
    const int lquad = lane >> 4;
    const int mtile = w >> 2;   // 0..3
    const int nq    = w & 3;    // 0..3
    const int s0    = blockIdx.x * SPB;

    // ---- Phase 0: stage weights + per-sample trig ----
    if (tid < 512)      ((float*)sW1s)[tid] = W1[tid];
    else if (tid < 640) sB1[tid - 512] = b1[tid - 512];
    else if (tid < 768) sB2[tid - 640] = b2[tid - 640];
    else if (tid < 896) sW3[tid - 768] = W3[tid - 768];

    float xz = 0.f, xw = 0.f;
    if (tid < SPB) {
        int g  = s0 + tid;
        int gc = g < B ? g : (B - 1);
        float4 x = reinterpret_cast<const float4*>(X)[gc];
        float s1, c1, s2, c2;
        __sincosf(x.x, &s1, &c1);
        __sincosf(x.y, &s2, &c2);
        sFeat[tid][0] = s1; sFeat[tid][1] = c1;
        sFeat[tid][2] = s2; sFeat[tid][3] = c2;
        xz = x.z; xw = x.w;
    }

    // W1 B-frag for GEMM3 (dV = G1 @ W1^T), K-quarter nq, kept in registers:
    // lane holds B[k=i=nq*32+lquad*8+idx][n=lrow] = (lrow<4) ? W1[lrow][i] : 0
    bf16x8 bW1 = {};
    if (lrow < 4) {
        const float4* wp = reinterpret_cast<const float4*>(
            &W1[lrow * HID + nq * 32 + lquad * 8]);
        float4 a = wp[0], b = wp[1];
        bW1[0] = (bf16)a.x; bW1[1] = (bf16)a.y; bW1[2] = (bf16)a.z; bW1[3] = (bf16)a.w;
        bW1[4] = (bf16)b.x; bW1[5] = (bf16)b.y; bW1[6] = (bf16)b.z; bW1[7] = (bf16)b.w;
    }

    // GEMM1 B-frags (W2 column segments), 2 tiles/wave
    #pragma unroll
    for (int tt = 0; tt < 2; ++tt) {
        int t  = 2 * w + tt;
        int kt = t >> 3, nt = t & 7;
        bf16x8 f;
        #pragma unroll
        for (int idx = 0; idx < 8; ++idx)
            f[idx] = (bf16)W2[(kt * 32 + lquad * 8 + idx) * HID + nt * 16 + lrow];
        *reinterpret_cast<bf16x8*>(&sW2F[(t * 64 + lane) * 8]) = f;
    }
    __syncthreads();

    // ---- Phase 1: H1 = tanh(feat @ W1 + b1), A-frag tile (mtile, kt=nq) ----
    {
        int srow = mtile * 16 + lrow;
        float f0 = sFeat[srow][0], f1 = sFeat[srow][1];
        float f2 = sFeat[srow][2], f3 = sFeat[srow][3];
        bf16x8 hf;
        #pragma unroll
        for (int idx = 0; idx < 8; ++idx) {
            int j = nq * 32 + lquad * 8 + idx;
            float z = sB1[j] + f0 * sW1s[0][j] + f1 * sW1s[1][j]
                             + f2 * sW1s[2][j] + f3 * sW1s[3][j];
            hf[idx] = (bf16)fast_tanh(z);
        }
        *reinterpret_cast<bf16x8*>(&sH1[((mtile * 4 + nq) * 64 + lane) * 8]) = hf;
    }
    __syncthreads();

    // ---- Phase 2: GEMM1  Z2 = H1 @ W2  (1 m-tile x 2 n-tiles per wave) ----
    floatx4 acc[2];
    acc[0] = floatx4{0.f, 0.f, 0.f, 0.f};
    acc[1] = floatx4{0.f, 0.f, 0.f, 0.f};
    #pragma unroll
    for (int kt = 0; kt < 4; ++kt) {
        bf16x8 a = *reinterpret_cast<const bf16x8*>(&sH1[((mtile * 4 + kt) * 64 + lane) * 8]);
        #pragma unroll
        for (int n = 0; n < 2; ++n) {
            int nt = nq * 2 + n;
            bf16x8 bfr = *reinterpret_cast<const bf16x8*>(&sW2F[((kt * 8 + nt) * 64 + lane) * 8]);
            acc[n] = __builtin_amdgcn_mfma_f32_16x16x32_bf16(a, bfr, acc[n], 0, 0, 0);
        }
    }

    // ---- Phase 3: G2 = (1 - tanh^2(Z2+b2)) * W3, scatter to A-frags ----
    #pragma unroll
    for (int n = 0; n < 2; ++n) {
        int nt = nq * 2 + n;
        int j  = nt * 16 + lrow;
        float bb = sB2[j], w3 = sW3[j];
        int kt2  = j >> 5;
        int lhi  = ((j >> 3) & 3) << 4;
        int idx2 = j & 7;
        #pragma unroll
        for (int r = 0; r < 4; ++r) {
            float h  = fast_tanh(acc[n][r] + bb);
            float g2 = (1.0f - h * h) * w3;
            sG2[((mtile * 4 + kt2) * 64 + ((lquad * 4 + r) | lhi)) * 8 + idx2] = (bf16)g2;
        }
    }
    __syncthreads(); // GEMM1 reads of sW2F done; phase-3 sG2 writes done

    // ---- Restage sW2F with GEMM2 B-frags (W2 row segments), 2 tiles/wave ----
    #pragma unroll
    for (int tt = 0; tt < 2; ++tt) {
        int t  = 2 * w + tt;
        int kt = t >> 3, nt = t & 7;
        const float4* rp = reinterpret_cast<const float4*>(
            &W2[(nt * 16 + lrow) * HID + kt * 32 + lquad * 8]);
        float4 r0 = rp[0], r1 = rp[1];
        bf16x8 g;
        g[0] = (bf16)r0.x; g[1] = (bf16)r0.y; g[2] = (bf16)r0.z; g[3] = (bf16)r0.w;
        g[4] = (bf16)r1.x; g[5] = (bf16)r1.y; g[6] = (bf16)r1.z; g[7] = (bf16)r1.w;
        *reinterpret_cast<bf16x8*>(&sW2F[(t * 64 + lane) * 8]) = g;
    }
    __syncthreads();

    // ---- Phase 4: GEMM2  S = G2 @ W2^T ----
    acc[0] = floatx4{0.f, 0.f, 0.f, 0.f};
    acc[1] = floatx4{0.f, 0.f, 0.f, 0.f};
    #pragma unroll
    for (int kt = 0; kt < 4; ++kt) {
        bf16x8 a = *reinterpret_cast<const bf16x8*>(&sG2[((mtile * 4 + kt) * 64 + lane) * 8]);
        #pragma unroll
        for (int n = 0; n < 2; ++n) {
            int nt = nq * 2 + n;
            bf16x8 bfr = *reinterpret_cast<const bf16x8*>(&sW2F[((kt * 8 + nt) * 64 + lane) * 8]);
            acc[n] = __builtin_amdgcn_mfma_f32_16x16x32_bf16(a, bfr, acc[n], 0, 0, 0);
        }
    }
    __syncthreads(); // all GEMM2 reads of sG2 done before G1 overwrites it

    // ---- Phase 5: G1 = (1-h1^2)*S, scatter to A-frags (reuse sG2) ----
    #pragma unroll
    for (int n = 0; n < 2; ++n) {
        int nt = nq * 2 + n;
        int i  = nt * 16 + lrow;
        int kt2  = i >> 5;
        int lhi  = ((i >> 3) & 3) << 4;
        int idx2 = i & 7;
        #pragma unroll
        for (int r = 0; r < 4; ++r) {
            int a_off = ((mtile * 4 + kt2) * 64 + ((lquad * 4 + r) | lhi)) * 8 + idx2;
            float h1 = (float)sH1[a_off];
            float g1 = (1.0f - h1 * h1) * acc[n][r];
            sG2[a_off] = (bf16)g1;
        }
    }
    __syncthreads();

    // ---- Phase 6: GEMM3  dV(partial over K-quarter nq) = G1 @ W1^T ----
    {
        bf16x8 a = *reinterpret_cast<const bf16x8*>(&sG2[((mtile * 4 + nq) * 64 + lane) * 8]);
        floatx4 d = __builtin_amdgcn_mfma_f32_16x16x32_bf16(
            a, bW1, floatx4{0.f, 0.f, 0.f, 0.f}, 0, 0, 0);
        if (lrow < 4) { // col = feat index k, rows = 4 samples
            #pragma unroll
            for (int r = 0; r < 4; ++r)
                sDV[nq][mtile * 16 + lquad * 4 + r][lrow] = d[r];
        }
    }
    __syncthreads();

    // ---- Phase 7: analytic dynamics + 2x2 solve (tid<64) ----
    if (tid < SPB) {
        int g = s0 + tid;
        if (g < B) {
            float4 d0 = *reinterpret_cast<const float4*>(&sDV[0][tid][0]);
            float4 d1 = *reinterpret_cast<const float4*>(&sDV[1][tid][0]);
            float4 d2 = *reinterpret_cast<const float4*>(&sDV[2][tid][0]);
            float4 d3 = *reinterpret_cast<const float4*>(&sDV[3][tid][0]);
            float dV0 = d0.x + d1.x + d2.x + d3.x;
            float dV1 = d0.y + d1.y + d2.y + d3.y;
            float dV2 = d0.z + d1.z + d2.z + d3.z;
            float dV3 = d0.w + d1.w + d2.w + d3.w;
            float s1 = sFeat[tid][0], c1 = sFeat[tid][1];
            float s2 = sFeat[tid][2], c2 = sFeat[tid][3];
            float w1 = xz, w2 = xw;
            float cosD = c1 * c2 + s1 * s2;
            float sinD = s1 * c2 - c1 * s2;
            float dVt1 = dV0 * c1 - dV1 * s1;   // dV/dt1
            float dVt2 = dV2 * c2 - dV3 * s2;   // dV/dt2
            float sT = w1 * w2 * sinD;          // dT/dt1 = -sT, dT/dt2 = +sT
            float cw = sinD * (w2 - w1);
            float rhs1 = (-sT - dVt1) - w2 * cw;
            float rhs2 = ( sT - dVt2) - w1 * cw;
            float det = 2.0f - cosD * cosD;     // det(M) in [1,2]
            float inv = 1.0f / det;
            float qdd1 = (rhs1 - cosD * rhs2) * inv;
            float qdd2 = (2.0f * rhs2 - cosD * rhs1) * inv;
            *reinterpret_cast<float4*>(&out[4 * g]) = make_float4(w1, w2, qdd1, qdd2);
        }
    }
}

extern "C" void kernel_launch(void* const* d_in, const int* in_sizes, int n_in,
                              void* d_out, int out_size, void* d_ws, size_t ws_size,
                              hipStream_t stream) {
    const float* X  = (const float*)d_in[0];
    const float* W1 = (const float*)d_in[1];
    const float* b1 = (const float*)d_in[2];
    const float* W2 = (const float*)d_in[3];
    const float* b2 = (const float*)d_in[4];
    const float* W3 = (const float*)d_in[5];
    // d_in[6] = b3: constant offset on V, vanishes in all gradients
    float* out = (float*)d_out;
    int B = in_sizes[0] / 4;
    int grid = (B + SPB - 1) / SPB;
    lnn_kernel<<<grid, TPB, 0, stream>>>(X, W1, b1, W2, b2, W3, out, B);
}